// Round 2
// baseline (2346.604 us; speedup 1.0000x reference)
//
#include <hip/hip_runtime.h>
#include <cstdint>
#include <cstddef>

#define TSTEPS 1024
#define NB 256
#define NI 128
#define NH 128
#define NC 18

typedef _Float16 half2_t __attribute__((ext_vector_type(2)));

__device__ __forceinline__ half2_t as_h2(uint32_t v){
  union { uint32_t u; half2_t h; } cv; cv.u = v; return cv.h;
}
__device__ __forceinline__ uint32_t pack_h2(float a, float b){
  half2_t h; h.x = (_Float16)a; h.y = (_Float16)b;
  union { half2_t h; uint32_t u; } cv; cv.h = h; return cv.u;
}
__device__ __forceinline__ float dot2f(half2_t a, half2_t b, float c){
#if __has_builtin(__builtin_amdgcn_fdot2)
  return __builtin_amdgcn_fdot2(a, b, c, false);   // v_dot2_f32_f16
#else
  return c + (float)a.x*(float)b.x + (float)a.y*(float)b.y;
#endif
}
__device__ __forceinline__ float fast_rcp(float x){
#if __has_builtin(__builtin_amdgcn_rcpf)
  return __builtin_amdgcn_rcpf(x);
#else
  return 1.f / x;
#endif
}
__device__ __forceinline__ float sigm(float v){
  v = fminf(fmaxf(v, -30.f), 30.f);
  return fast_rcp(1.f + __expf(-v));
}
__device__ __forceinline__ float tanhx(float v){
  v = fminf(fmaxf(v, -15.f), 15.f);
  float e = __expf(2.f*v);
  return (e - 1.f) * fast_rcp(e + 1.f);
}

// 16 half2 (32 elems) of src dotted against 4 gate weight rows.
__device__ __forceinline__ void dots16(const uint32_t* __restrict__ src,
                                       const half2_t (&w)[4][16],
                                       float& a0, float& a1, float& a2, float& a3){
  const uint4* vv = (const uint4*)src;
#pragma unroll
  for (int ch = 0; ch < 4; ++ch){
    uint4 v = vv[ch];                       // broadcast ds_read_b128 (wave-uniform addr)
    uint32_t wd[4] = {v.x, v.y, v.z, v.w};
#pragma unroll
    for (int j = 0; j < 4; ++j){
      half2_t hx = as_h2(wd[j]);
      const int k = ch*4 + j;
      a0 = dot2f(w[0][k], hx, a0);
      a1 = dot2f(w[1][k], hx, a1);
      a2 = dot2f(w[2][k], hx, a2);
      a3 = dot2f(w[3][k], hx, a3);
    }
  }
}

// One block per batch row, 1024 threads (16 waves).
// Waves 0-7  (hh side): recurrent h @ W_hh^T, gate finalize, c/h update.
// Waves 8-15 (x  side): x @ W_ih^T pipelined 2 steps ahead; x prefetch; fused head.
// Per-thread weights: 64 half2 VGPRs (4 gates x 16 half2) -> fits 128-VGPR budget.
__global__ __launch_bounds__(1024, 4) void lstm_fused(
    const float* __restrict__ x,      // [T,B,I]
    const float* __restrict__ h0,     // [B,H]
    const float* __restrict__ c0,     // [B,H]
    const float* __restrict__ Wih,    // [4H,I]
    const float* __restrict__ Whh,    // [4H,H]
    const float* __restrict__ bih,    // [4H]
    const float* __restrict__ bhh,    // [4H]
    const float* __restrict__ fcW,    // [18,H]
    const float* __restrict__ fcb,    // [18]
    float* __restrict__ out,          // [T,B,18]
    float* __restrict__ hT,           // [B,H]
    float* __restrict__ cT)           // [B,H]
{
  const int b    = blockIdx.x;
  const int tid  = threadIdx.x;
  const bool hh_side = tid < 512;
  const int tid2 = tid - 512;         // valid on x side
  const int c    = tid & 127;
  const int s    = (tid >> 7) & 3;    // k-slice [32s, 32s+32)

  __shared__ __align__(16) uint32_t h2[2][64];        // h_{t-1} as f16 pairs (buf t&1)
  __shared__ __align__(16) uint32_t xf16[4][64];      // x rows fifo, f16 pairs
  __shared__ __align__(16) float pbh[3][4][128];      // hh partials  [s-1][gate][c]
  __shared__ __align__(16) float pbx[2][3][4][128];   // x  partials, dbuf
  __shared__ __align__(16) float xg[2][4][128];       // finalized x-gates (+bias), dbuf
  __shared__ __align__(16) float hpb[2][72];          // head partials, dbuf

  // ---- weights into registers (f16 pairs): W_hh for hh side, W_ih for x side ----
  half2_t w[4][16];
  {
    const float* Wbase = hh_side ? Whh : Wih;
#pragma unroll
    for (int q = 0; q < 4; ++q){
      const float2* wp = (const float2*)(Wbase + (size_t)(q*128 + c)*128 + 32*s);
#pragma unroll
      for (int k = 0; k < 16; ++k){
        float2 f = wp[k];
        half2_t a; a.x = (_Float16)f.x; a.y = (_Float16)f.y;
        w[q][k] = a;
      }
    }
  }

  // ---- x-side sub-roles (phase B duties) ----
  const bool is_xfin = !hh_side && (s == 0);                       // tid2   0..127
  const bool is_pref = !hh_side && tid2 >= 128 && tid2 < 192;      // tid2 128..191
  const bool is_hp   = !hh_side && tid2 >= 192 && tid2 < 264;      // tid2 192..263
  const bool is_hf   = !hh_side && tid2 >= 264 && tid2 < 282;      // tid2 264..281

  half2_t wfc[16];
  if (is_hp){
    const int j  = (tid2 - 192) >> 2;
    const int ss = (tid2 - 192) & 3;
    const float2* wf = (const float2*)(fcW + (size_t)j*NH + 32*ss);
#pragma unroll
    for (int k = 0; k < 16; ++k){
      float2 f = wf[k];
      half2_t a; a.x = (_Float16)f.x; a.y = (_Float16)f.y;
      wfc[k] = a;
    }
  }

  float bq0=0.f, bq1=0.f, bq2=0.f, bq3=0.f;
  if (is_xfin){
    bq0 = bih[0*128+c] + bhh[0*128+c];
    bq1 = bih[1*128+c] + bhh[1*128+c];
    bq2 = bih[2*128+c] + bhh[2*128+c];
    bq3 = bih[3*128+c] + bhh[3*128+c];
  }
  const float myfcb = is_hf ? fcb[tid2 - 264] : 0.f;

  float cst = 0.f;
  if (hh_side && s == 0) cst = c0[(size_t)b*NH + c];

  // ---- prime: h0, x rows 0..3 into LDS; xA=x4, xB=x5 ----
  float2 xA = make_float2(0.f,0.f), xB = make_float2(0.f,0.f);
  if (is_pref){
    const int l = tid2 - 128;           // 0..63 (float2 lane)
    float2 hv = ((const float2*)(h0 + (size_t)b*NH))[l];
    h2[0][l] = pack_h2(hv.x, hv.y);
#pragma unroll
    for (int r = 0; r < 4; ++r){
      float2 f = ((const float2*)(x + ((size_t)r*NB + b)*NI))[l];
      xf16[r][l] = pack_h2(f.x, f.y);
    }
    xA = ((const float2*)(x + ((size_t)4*NB + b)*NI))[l];
    xB = ((const float2*)(x + ((size_t)5*NB + b)*NI))[l];
  }
  __syncthreads();

  float axp0=0.f, axp1=0.f, axp2=0.f, axp3=0.f;   // x partials for step t+1 (s==0 carry)

  for (int t = -2; t < TSTEPS; ++t){
    float a0=0.f, a1=0.f, a2=0.f, a3=0.f;
    // ================ phase A: partial dots ================
    if (hh_side){
      if (t >= 0){
        dots16(&h2[t&1][16*s], w, a0, a1, a2, a3);
        if (s != 0){
          pbh[s-1][0][c] = a0;
          pbh[s-1][1][c] = a1;
          pbh[s-1][2][c] = a2;
          pbh[s-1][3][c] = a3;
        }
      }
    } else {
      const int tt = t + 2;
      if (tt < TSTEPS){
        dots16(&xf16[tt&3][16*s], w, a0, a1, a2, a3);
        if (s != 0){
          pbx[tt&1][s-1][0][c] = a0;
          pbx[tt&1][s-1][1][c] = a1;
          pbx[tt&1][s-1][2][c] = a2;
          pbx[tt&1][s-1][3][c] = a3;
        }
      }
    }
    __syncthreads();
    // ================ phase B ================
    if (hh_side){
      if (t >= 0 && s == 0){
        const int hp = t & 1;
        float gi = a0 + pbh[0][0][c] + pbh[1][0][c] + pbh[2][0][c] + xg[hp][0][c];
        float gf = a1 + pbh[0][1][c] + pbh[1][1][c] + pbh[2][1][c] + xg[hp][1][c];
        float gg = a2 + pbh[0][2][c] + pbh[1][2][c] + pbh[2][2][c] + xg[hp][2][c];
        float go = a3 + pbh[0][3][c] + pbh[1][3][c] + pbh[2][3][c] + xg[hp][3][c];
        float iv = sigm(gi);
        float fv = sigm(gf);
        float gv = tanhx(gg);
        float ov = sigm(go);
        cst = fv*cst + iv*gv;
        float hval = ov * tanhx(cst);
        ((_Float16*)&h2[hp^1][0])[c] = (_Float16)hval;     // h_t for step t+1
        if (t == TSTEPS-1){
          hT[(size_t)b*NH + c] = hval;
          cT[(size_t)b*NH + c] = cst;
        }
      }
    } else if (is_xfin){
      const int tf = t + 1;
      if (tf >= 0 && tf < TSTEPS){
        const int fp = tf & 1;
        xg[fp][0][c] = axp0 + pbx[fp][0][0][c] + pbx[fp][1][0][c] + pbx[fp][2][0][c] + bq0;
        xg[fp][1][c] = axp1 + pbx[fp][0][1][c] + pbx[fp][1][1][c] + pbx[fp][2][1][c] + bq1;
        xg[fp][2][c] = axp2 + pbx[fp][0][2][c] + pbx[fp][1][2][c] + pbx[fp][2][2][c] + bq2;
        xg[fp][3][c] = axp3 + pbx[fp][0][3][c] + pbx[fp][1][3][c] + pbx[fp][2][3][c] + bq3;
      }
    } else if (is_pref){
      if (t >= 0){
        const int l = tid2 - 128;
        xf16[(t+4)&3][l] = pack_h2(xA.x, xA.y);            // x_{t+4}
        xA = xB;
        int tn = t + 6; if (tn > TSTEPS-1) tn = TSTEPS-1;
        xB = ((const float2*)(x + ((size_t)tn*NB + b)*NI))[l];
      }
    } else if (is_hp){
      if (t >= 1){                                          // head partial for out[t-1]
        const int ss = (tid2 - 192) & 3;
        const uint4* hv2 = (const uint4*)&h2[t&1][16*ss];
        float p = 0.f;
#pragma unroll
        for (int ch = 0; ch < 4; ++ch){
          uint4 v = hv2[ch];
          uint32_t wd[4] = {v.x, v.y, v.z, v.w};
#pragma unroll
          for (int j = 0; j < 4; ++j)
            p = dot2f(wfc[ch*4 + j], as_h2(wd[j]), p);
        }
        hpb[t&1][tid2 - 192] = p;
      }
    } else if (is_hf){
      if (t >= 2){                                          // finalize out[t-2]
        const int j = tid2 - 264;
        float4 p = *(const float4*)&hpb[(t-1)&1][4*j];
        out[(size_t)(t-2)*NB*NC + (size_t)b*NC + j] = p.x + p.y + p.z + p.w + myfcb;
      }
    }
    if (is_xfin){ axp0 = a0; axp1 = a1; axp2 = a2; axp3 = a3; }
    __syncthreads();
  }

  // ---- epilogue: out[T-2] and out[T-1] ----
  if (is_hf){
    const int j = tid2 - 264;
    float4 p = *(const float4*)&hpb[(TSTEPS-1)&1][4*j];
    out[(size_t)(TSTEPS-2)*NB*NC + (size_t)b*NC + j] = p.x + p.y + p.z + p.w + myfcb;
  }
  if (is_hp){
    const int ss = (tid2 - 192) & 3;
    const uint4* hv2 = (const uint4*)&h2[TSTEPS & 1][16*ss];  // h_{T-1}
    float p = 0.f;
#pragma unroll
    for (int ch = 0; ch < 4; ++ch){
      uint4 v = hv2[ch];
      uint32_t wd[4] = {v.x, v.y, v.z, v.w};
#pragma unroll
      for (int j = 0; j < 4; ++j)
        p = dot2f(wfc[ch*4 + j], as_h2(wd[j]), p);
    }
    hpb[TSTEPS & 1][tid2 - 192] = p;
  }
  __syncthreads();
  if (is_hf){
    const int j = tid2 - 264;
    float4 p = *(const float4*)&hpb[TSTEPS & 1][4*j];
    out[(size_t)(TSTEPS-1)*NB*NC + (size_t)b*NC + j] = p.x + p.y + p.z + p.w + myfcb;
  }
}

extern "C" void kernel_launch(void* const* d_in, const int* in_sizes, int n_in,
                              void* d_out, int out_size, void* d_ws, size_t ws_size,
                              hipStream_t stream) {
  (void)in_sizes; (void)n_in; (void)d_ws; (void)ws_size; (void)out_size;
  const float* x   = (const float*)d_in[0];
  const float* h0  = (const float*)d_in[1];
  const float* c0  = (const float*)d_in[2];
  const float* Wih = (const float*)d_in[3];
  const float* Whh = (const float*)d_in[4];
  const float* bih = (const float*)d_in[5];
  const float* bhh = (const float*)d_in[6];
  const float* fcW = (const float*)d_in[7];
  const float* fcb = (const float*)d_in[8];
  float* out = (float*)d_out;
  float* hT  = out + (size_t)TSTEPS*NB*NC;   // 4,718,592
  float* cT  = hT + (size_t)NB*NH;           // +32,768
  hipLaunchKernelGGL(lstm_fused, dim3(NB), dim3(1024), 0, stream,
                     x, h0, c0, Wih, Whh, bih, bhh, fcW, fcb, out, hT, cT);
}

// Round 3
// 1453.941 us; speedup vs baseline: 1.6140x; 1.6140x over previous
//
#include <hip/hip_runtime.h>
#include <cstdint>
#include <cstddef>

#define TSTEPS 1024
#define NB 256
#define NI 128
#define NH 128
#define NC 18
#define CH 32
#define NCHUNK (TSTEPS/CH)   // 32

typedef _Float16 half2_t __attribute__((ext_vector_type(2)));

__device__ __forceinline__ half2_t as_h2(uint32_t v){
  union { uint32_t u; half2_t h; } cv; cv.u = v; return cv.h;
}
__device__ __forceinline__ half2_t pk(float a, float b){
  half2_t h; h.x = (_Float16)a; h.y = (_Float16)b; return h;
}
__device__ __forceinline__ uint32_t pku(float a, float b){
  union { half2_t h; uint32_t u; } cv; cv.h = pk(a,b); return cv.u;
}
__device__ __forceinline__ float dot2f(half2_t a, half2_t b, float c){
#if __has_builtin(__builtin_amdgcn_fdot2)
  return __builtin_amdgcn_fdot2(a, b, c, false);   // v_dot2_f32_f16
#else
  return c + (float)a.x*(float)b.x + (float)a.y*(float)b.y;
#endif
}
__device__ __forceinline__ float fast_rcp(float x){
#if __has_builtin(__builtin_amdgcn_rcpf)
  return __builtin_amdgcn_rcpf(x);
#else
  return 1.f / x;
#endif
}
__device__ __forceinline__ float sigm(float v){
  v = fminf(fmaxf(v, -30.f), 30.f);
  return fast_rcp(1.f + __expf(-v));
}
__device__ __forceinline__ float tanhx(float v){
  v = fminf(fmaxf(v, -15.f), 15.f);
  float e = __expf(2.f*v);
  return (e - 1.f) * fast_rcp(e + 1.f);
}

// 64 dot2 of a 128-elem f16 vector (16 uint4 in LDS, wave-uniform broadcast)
// against 64 resident half2 weights; 4 independent accumulation chains.
__device__ __forceinline__ float dots64(const uint4* __restrict__ vb,
                                        const half2_t (&w)[64], float seed){
  float a0 = seed, a1 = 0.f, a2 = 0.f, a3 = 0.f;
#pragma unroll
  for (int q = 0; q < 4; ++q){
    uint4 v0 = vb[q], v1 = vb[4+q], v2 = vb[8+q], v3 = vb[12+q];
    a0 = dot2f(w[   4*q+0], as_h2(v0.x), a0);
    a1 = dot2f(w[16+4*q+0], as_h2(v1.x), a1);
    a2 = dot2f(w[32+4*q+0], as_h2(v2.x), a2);
    a3 = dot2f(w[48+4*q+0], as_h2(v3.x), a3);
    a0 = dot2f(w[   4*q+1], as_h2(v0.y), a0);
    a1 = dot2f(w[16+4*q+1], as_h2(v1.y), a1);
    a2 = dot2f(w[32+4*q+1], as_h2(v2.y), a2);
    a3 = dot2f(w[48+4*q+1], as_h2(v3.y), a3);
    a0 = dot2f(w[   4*q+2], as_h2(v0.z), a0);
    a1 = dot2f(w[16+4*q+2], as_h2(v1.z), a1);
    a2 = dot2f(w[32+4*q+2], as_h2(v2.z), a2);
    a3 = dot2f(w[48+4*q+2], as_h2(v3.z), a3);
    a0 = dot2f(w[   4*q+3], as_h2(v0.w), a0);
    a1 = dot2f(w[16+4*q+3], as_h2(v1.w), a1);
    a2 = dot2f(w[32+4*q+3], as_h2(v2.w), a2);
    a3 = dot2f(w[48+4*q+3], as_h2(v3.w), a3);
  }
  return (a0 + a1) + (a2 + a3);
}

// One persistent block per batch row. 512 threads, thread g owns gate g.
// Chunked pipeline: stage x -> compute x-gates (bulk) -> 32 recurrent steps
// (64 hh-dot2/thread/step, no cross-thread reduction) -> fused head.
__global__ __launch_bounds__(512, 2) void lstm_chunk(
    const float* __restrict__ x,      // [T,B,I]
    const float* __restrict__ h0,     // [B,H]
    const float* __restrict__ c0,     // [B,H]
    const float* __restrict__ Wih,    // [4H,I]
    const float* __restrict__ Whh,    // [4H,H]
    const float* __restrict__ bih,    // [4H]
    const float* __restrict__ bhh,    // [4H]
    const float* __restrict__ fcW,    // [18,H]
    const float* __restrict__ fcb,    // [18]
    float* __restrict__ out,          // [T,B,18]
    float* __restrict__ hT,           // [B,H]
    float* __restrict__ cT)           // [B,H]
{
  const int b  = blockIdx.x;
  const int g  = threadIdx.x;        // gate id 0..511
  const int c  = g & 127;            // cell id
  const int gq = g >> 7;             // 0=i,1=f,2=g,3=o (wave-uniform)

  __shared__ __align__(16) uint32_t xs[CH][64];     // x chunk, f16 pairs   (8 KB)
  __shared__ __align__(16) _Float16 xg[CH][512];    // x-gates + bias, f16  (32 KB)
  __shared__ __align__(16) uint32_t h2[64];         // h_{t-1}, f16 pairs   (256 B)
  __shared__ __align__(16) float    act[512];       // activated gates      (2 KB)
  __shared__ __align__(16) uint32_t hhist[CH][68];  // h history (+pad)     (8.5 KB)
  __shared__ __align__(16) uint32_t fcw[NC][66];    // fcW f16 pairs (+pad) (4.6 KB)

  // ---- persistent W_hh row for gate g: 64 half2 in VGPRs ----
  half2_t w[64];
  {
    const float4* wr = (const float4*)(Whh + (size_t)g*NH);
#pragma unroll
    for (int i = 0; i < 32; ++i){
      float4 f = wr[i];
      w[2*i]   = pk(f.x, f.y);
      w[2*i+1] = pk(f.z, f.w);
    }
  }
  const float bq = bih[g] + bhh[g];
  float cst = c0[(size_t)b*NH + c];      // replicated across the 4 gate groups

  // ---- init h2 (h0) and fcw LDS ----
  if (g < 64){
    float2 hv = ((const float2*)(h0 + (size_t)b*NH))[g];
    h2[g] = pku(hv.x, hv.y);
  }
#pragma unroll
  for (int r = 0; r < 3; ++r){
    int idx = g + 512*r;                 // 18*64 = 1152 u32 targets
    if (idx < NC*64){
      int j = idx >> 6, k = idx & 63;
      float2 f = ((const float2*)(fcW + (size_t)j*NH))[k];
      fcw[j][k] = pku(f.x, f.y);
    }
  }
  __syncthreads();

  for (int ck = 0; ck < NCHUNK; ++ck){
    const int t0 = ck*CH;

    // ---------- stage x chunk into LDS (f16 pairs) ----------
#pragma unroll
    for (int u = 0; u < 2; ++u){
      int f4i = g + 512*u;               // 32 rows x 32 float4
      int tt = f4i >> 5, k4 = f4i & 31;
      float4 f = ((const float4*)(x + ((size_t)(t0+tt)*NB + b)*NI))[k4];
      uint2 pp; pp.x = pku(f.x, f.y); pp.y = pku(f.z, f.w);
      *(uint2*)&xs[tt][2*k4] = pp;
    }
    __syncthreads();

    // ---------- bulk x-gates: xg[tt][g] = x_t . Wih[g] + bias ----------
    {
      int lofs = 0;
      asm volatile("" : "+v"(lofs));     // block LICM: keep Wih loads per-chunk
      const float4* wrp = (const float4*)(Wih + (size_t)g*NI + lofs);
      half2_t wx[64];
#pragma unroll
      for (int i = 0; i < 32; ++i){
        float4 f = wrp[i];
        wx[2*i]   = pk(f.x, f.y);
        wx[2*i+1] = pk(f.z, f.w);
      }
      for (int tt = 0; tt < CH; ++tt){
        float v = dots64((const uint4*)&xs[tt][0], wx, bq);
        xg[tt][g] = (_Float16)v;
      }
    }
    __syncthreads();

    // ---------- 32 recurrent steps ----------
    for (int tt = 0; tt < CH; ++tt){
      float seed = (float)xg[tt][g];
      float gv = dots64((const uint4*)&h2[0], w, seed);
      float av = (gq == 2) ? tanhx(gv) : sigm(gv);
      act[g] = av;
      __syncthreads();
      float iv = act[c], fv = act[128+c], gg = act[256+c], ov = act[384+c];
      cst = fv*cst + iv*gg;                       // replicated update (uniform)
      float hval = ov * tanhx(cst);
      if (g < 128){
        ((_Float16*)h2)[c]            = (_Float16)hval;
        ((_Float16*)&hhist[tt][0])[c] = (_Float16)hval;
      }
      __syncthreads();
    }

    // ---------- fused head for this chunk: out[t] = h_t . fcW^T + fcb ----------
    {
      const int tt = g >> 4;             // 0..31
      const int jb = g & 15;
      const uint4* hb = (const uint4*)&hhist[tt][0];
#pragma unroll
      for (int jj = 0; jj < 2; ++jj){
        const int j = jj*16 + jb;
        if (j < NC){
          const uint2* fw = (const uint2*)&fcw[j][0];
          float a0=0.f, a1=0.f, a2=0.f, a3=0.f;
#pragma unroll
          for (int q = 0; q < 4; ++q){
            uint4 v0 = hb[q], v1 = hb[4+q], v2 = hb[8+q], v3 = hb[12+q];
            uint2 f0a = fw[2*q],    f0b = fw[2*q+1];
            uint2 f1a = fw[8+2*q],  f1b = fw[8+2*q+1];
            uint2 f2a = fw[16+2*q], f2b = fw[16+2*q+1];
            uint2 f3a = fw[24+2*q], f3b = fw[24+2*q+1];
            a0 = dot2f(as_h2(f0a.x), as_h2(v0.x), a0);
            a1 = dot2f(as_h2(f1a.x), as_h2(v1.x), a1);
            a2 = dot2f(as_h2(f2a.x), as_h2(v2.x), a2);
            a3 = dot2f(as_h2(f3a.x), as_h2(v3.x), a3);
            a0 = dot2f(as_h2(f0a.y), as_h2(v0.y), a0);
            a1 = dot2f(as_h2(f1a.y), as_h2(v1.y), a1);
            a2 = dot2f(as_h2(f2a.y), as_h2(v2.y), a2);
            a3 = dot2f(as_h2(f3a.y), as_h2(v3.y), a3);
            a0 = dot2f(as_h2(f0b.x), as_h2(v0.z), a0);
            a1 = dot2f(as_h2(f1b.x), as_h2(v1.z), a1);
            a2 = dot2f(as_h2(f2b.x), as_h2(v2.z), a2);
            a3 = dot2f(as_h2(f3b.x), as_h2(v3.z), a3);
            a0 = dot2f(as_h2(f0b.y), as_h2(v0.w), a0);
            a1 = dot2f(as_h2(f1b.y), as_h2(v1.w), a1);
            a2 = dot2f(as_h2(f2b.y), as_h2(v2.w), a2);
            a3 = dot2f(as_h2(f3b.y), as_h2(v3.w), a3);
          }
          out[(size_t)(t0+tt)*NB*NC + (size_t)b*NC + j] =
              (a0+a1) + (a2+a3) + fcb[j];
        }
      }
    }
    __syncthreads();   // protect xs/xg/hhist for next chunk
  }

  // ---------- final hT / cT ----------
  if (g < 128){
    hT[(size_t)b*NH + c] = (float)((_Float16*)h2)[c];
    cT[(size_t)b*NH + c] = cst;
  }
}

extern "C" void kernel_launch(void* const* d_in, const int* in_sizes, int n_in,
                              void* d_out, int out_size, void* d_ws, size_t ws_size,
                              hipStream_t stream) {
  (void)in_sizes; (void)n_in; (void)d_ws; (void)ws_size; (void)out_size;
  const float* x   = (const float*)d_in[0];
  const float* h0  = (const float*)d_in[1];
  const float* c0  = (const float*)d_in[2];
  const float* Wih = (const float*)d_in[3];
  const float* Whh = (const float*)d_in[4];
  const float* bih = (const float*)d_in[5];
  const float* bhh = (const float*)d_in[6];
  const float* fcW = (const float*)d_in[7];
  const float* fcb = (const float*)d_in[8];
  float* out = (float*)d_out;
  float* hT  = out + (size_t)TSTEPS*NB*NC;   // 4,718,592
  float* cT  = hT + (size_t)NB*NH;           // +32,768
  hipLaunchKernelGGL(lstm_chunk, dim3(NB), dim3(512), 0, stream,
                     x, h0, c0, Wih, Whh, bih, bhh, fcW, fcb, out, hT, cT);
}

// Round 4
// 1025.317 us; speedup vs baseline: 2.2887x; 1.4180x over previous
//
#include <hip/hip_runtime.h>
#include <cstdint>
#include <cstddef>

#define TSTEPS 1024
#define NB 256
#define NI 128
#define NH 128
#define NC 18
#define CH 32
#define NCHUNK (TSTEPS/CH)   // 32

typedef _Float16 f16x8 __attribute__((ext_vector_type(8)));
typedef float    f32x4 __attribute__((ext_vector_type(4)));
typedef _Float16 half2_t __attribute__((ext_vector_type(2)));

__device__ __forceinline__ half2_t as_h2(uint32_t v){
  union { uint32_t u; half2_t h; } cv; cv.u = v; return cv.h;
}
__device__ __forceinline__ uint32_t pku(float a, float b){
  union { half2_t h; uint32_t u; } cv; cv.h.x=(_Float16)a; cv.h.y=(_Float16)b; return cv.u;
}
__device__ __forceinline__ float dot2f(half2_t a, half2_t b, float c){
#if __has_builtin(__builtin_amdgcn_fdot2)
  return __builtin_amdgcn_fdot2(a, b, c, false);
#else
  return c + (float)a.x*(float)b.x + (float)a.y*(float)b.y;
#endif
}
__device__ __forceinline__ float fast_rcp(float x){
#if __has_builtin(__builtin_amdgcn_rcpf)
  return __builtin_amdgcn_rcpf(x);
#else
  return 1.f / x;
#endif
}
__device__ __forceinline__ float sigm(float v){
  v = fminf(fmaxf(v, -30.f), 30.f);
  return fast_rcp(1.f + __expf(-v));
}
__device__ __forceinline__ float tanhx(float v){
  v = fminf(fmaxf(v, -15.f), 15.f);
  float e = __expf(2.f*v);
  return (e - 1.f) * fast_rcp(e + 1.f);
}
// 8 consecutive f32 -> f16x8 (one MFMA operand row-slice)
__device__ __forceinline__ f16x8 ldrow_f16(const float* base){
  float4 f0 = ((const float4*)base)[0];
  float4 f1 = ((const float4*)base)[1];
  f16x8 r;
  r[0]=(_Float16)f0.x; r[1]=(_Float16)f0.y; r[2]=(_Float16)f0.z; r[3]=(_Float16)f0.w;
  r[4]=(_Float16)f1.x; r[5]=(_Float16)f1.y; r[6]=(_Float16)f1.z; r[7]=(_Float16)f1.w;
  return r;
}

// One block per batch row, 512 threads (8 waves).
// Gate permutation: wave w, gate-type q (i,f,g,o), cell = w*16 + n (n=lane&15).
// Recurrent step = 16 MFMA/wave (4 q-tiles x 4 k-tiles, M=1 used of 16);
// i,f,g,o for a cell land in the SAME lane (4 accs) -> in-lane activation.
// x-projection: per-chunk MFMA GEMM XG[32,512] seeded with bias, f32 in LDS.
__global__ __launch_bounds__(512, 2) void lstm_mfma(
    const float* __restrict__ x,      // [T,B,I]
    const float* __restrict__ h0,     // [B,H]
    const float* __restrict__ c0,     // [B,H]
    const float* __restrict__ Wih,    // [4H,I]
    const float* __restrict__ Whh,    // [4H,H]
    const float* __restrict__ bih,    // [4H]
    const float* __restrict__ bhh,    // [4H]
    const float* __restrict__ fcW,    // [18,H]
    const float* __restrict__ fcb,    // [18]
    float* __restrict__ out,          // [T,B,18]
    float* __restrict__ hT,           // [B,H]
    float* __restrict__ cT)           // [B,H]
{
  const int b    = blockIdx.x;
  const int tid  = threadIdx.x;
  const int w    = tid >> 6;      // wave 0..7
  const int l    = tid & 63;
  const int n    = l & 15;        // tile col
  const int quad = l >> 4;        // k-chunk within frag

  __shared__ __align__(16) _Float16 xs[CH][136];    // x chunk f16 (+pad)     8704 B
  __shared__ __align__(16) float    xg[CH][512];    // x-gates f32           65536 B
  __shared__ __align__(16) _Float16 hbuf[2][128];   // h double buffer         512 B
  __shared__ __align__(16) _Float16 hist[CH][128];  // h history             8192 B
  __shared__ __align__(16) uint32_t fcw[NC][66];    // head W f16 (+pad)     4752 B

  // ---- persistent Whh B-frags: [q][kt], 64 VGPRs ----
  f16x8 whh[4][4];
#pragma unroll
  for (int q = 0; q < 4; ++q){
    const int row = q*128 + w*16 + n;
#pragma unroll
    for (int kt = 0; kt < 4; ++kt)
      whh[q][kt] = ldrow_f16(Whh + (size_t)row*NH + kt*32 + quad*8);
  }
  float biasq[4];
#pragma unroll
  for (int q = 0; q < 4; ++q){
    const int g = q*128 + w*16 + n;
    biasq[q] = bih[g] + bhh[g];
  }
  float cst = c0[(size_t)b*NH + w*16 + n];   // valid lanes n==l<16

  if (tid < 128) hbuf[0][tid] = (_Float16)h0[(size_t)b*NH + tid];
#pragma unroll
  for (int r = 0; r < 3; ++r){
    int idx = tid + 512*r;                   // 18*64 = 1152 targets
    if (idx < NC*64){
      int j = idx >> 6, k = idx & 63;
      float2 f = ((const float2*)(fcW + (size_t)j*NH))[k];
      fcw[j][k] = pku(f.x, f.y);
    }
  }
  __syncthreads();

  int p = 0;
  f16x8 afr[4] = { (f16x8)(_Float16)0, (f16x8)(_Float16)0,
                   (f16x8)(_Float16)0, (f16x8)(_Float16)0 };

  for (int ck = 0; ck < NCHUNK; ++ck){
    const int t0 = ck*CH;

    // ---------- stage x chunk -> xs (f16) ----------
#pragma unroll
    for (int u = 0; u < 2; ++u){
      int f4i = tid + 512*u;                 // 32 rows x 32 float4
      int tt = f4i >> 5, k4 = f4i & 31;
      float4 f = ((const float4*)(x + ((size_t)(t0+tt)*NB + b)*NI))[k4];
      union { _Float16 h[4]; uint2 u2; } pk4;
      pk4.h[0]=(_Float16)f.x; pk4.h[1]=(_Float16)f.y;
      pk4.h[2]=(_Float16)f.z; pk4.h[3]=(_Float16)f.w;
      *(uint2*)&xs[tt][4*k4] = pk4.u2;
    }
    __syncthreads();

    // ---------- x-GEMM: XG[32,512] = X @ Wih^T + bias (MFMA) ----------
    {
      f16x8 xa[2][4];                        // A-frags [mt][kt]
#pragma unroll
      for (int mt = 0; mt < 2; ++mt)
#pragma unroll
        for (int kt = 0; kt < 4; ++kt)
          xa[mt][kt] = *(const f16x8*)&xs[mt*16 + n][kt*32 + quad*8];

      int lofs = 0;
      asm volatile("" : "+v"(lofs));         // keep Wih loads per-chunk (no LICM)
#pragma unroll
      for (int q = 0; q < 4; ++q){
        const int row = q*128 + w*16 + n;
        f16x8 wb[4];
#pragma unroll
        for (int kt = 0; kt < 4; ++kt)
          wb[kt] = ldrow_f16(Wih + (size_t)row*NI + kt*32 + quad*8 + lofs);
#pragma unroll
        for (int mt = 0; mt < 2; ++mt){
          f32x4 acc = { biasq[q], biasq[q], biasq[q], biasq[q] };
#pragma unroll
          for (int kt = 0; kt < 4; ++kt)
            acc = __builtin_amdgcn_mfma_f32_16x16x32_f16(xa[mt][kt], wb[kt], acc, 0, 0, 0);
#pragma unroll
          for (int r = 0; r < 4; ++r)
            xg[mt*16 + quad*4 + r][w*64 + q*16 + n] = acc[r];
        }
      }
    }
    __syncthreads();

    // ---------- 32 recurrent steps ----------
    for (int tt = 0; tt < CH; ++tt){
      float sg0 = xg[tt][w*64 +  0 + n];
      float sg1 = xg[tt][w*64 + 16 + n];
      float sg2 = xg[tt][w*64 + 32 + n];
      float sg3 = xg[tt][w*64 + 48 + n];
      if (n == 0){                           // lanes 0,16,32,48 hold the real A row
#pragma unroll
        for (int kt = 0; kt < 4; ++kt)
          afr[kt] = *(const f16x8*)&hbuf[p][kt*32 + quad*8];
      }
      float gate[4];
      float sg[4] = { sg0, sg1, sg2, sg3 };
#pragma unroll
      for (int q = 0; q < 4; ++q){
        f32x4 aA = { sg[q], sg[q], sg[q], sg[q] };
        aA = __builtin_amdgcn_mfma_f32_16x16x32_f16(afr[0], whh[q][0], aA, 0, 0, 0);
        aA = __builtin_amdgcn_mfma_f32_16x16x32_f16(afr[1], whh[q][1], aA, 0, 0, 0);
        f32x4 aB = { 0.f, 0.f, 0.f, 0.f };
        aB = __builtin_amdgcn_mfma_f32_16x16x32_f16(afr[2], whh[q][2], aB, 0, 0, 0);
        aB = __builtin_amdgcn_mfma_f32_16x16x32_f16(afr[3], whh[q][3], aB, 0, 0, 0);
        gate[q] = aA[0] + aB[0];
      }
      if (l < 16){
        float iv = sigm(gate[0]);
        float fv = sigm(gate[1]);
        float gv = tanhx(gate[2]);
        float ov = sigm(gate[3]);
        cst = fv*cst + iv*gv;
        float hval = ov * tanhx(cst);
        _Float16 hh = (_Float16)hval;
        hbuf[p^1][w*16 + l] = hh;
        hist[tt][w*16 + l]  = hh;
      }
      __syncthreads();
      p ^= 1;
    }

    // ---------- fused head for this chunk ----------
    {
      const int tt = tid >> 4;               // 0..31
      const int jb = tid & 15;
      const uint4* hb = (const uint4*)&hist[tt][0];
#pragma unroll
      for (int jj = 0; jj < 2; ++jj){
        const int j = jj*16 + jb;
        if (j < NC){
          const uint2* fw = (const uint2*)&fcw[j][0];
          float a0=0.f, a1=0.f, a2=0.f, a3=0.f;
#pragma unroll
          for (int q = 0; q < 4; ++q){
            uint4 v0 = hb[q], v1 = hb[4+q], v2 = hb[8+q], v3 = hb[12+q];
            uint2 f0a = fw[2*q],    f0b = fw[2*q+1];
            uint2 f1a = fw[8+2*q],  f1b = fw[8+2*q+1];
            uint2 f2a = fw[16+2*q], f2b = fw[16+2*q+1];
            uint2 f3a = fw[24+2*q], f3b = fw[24+2*q+1];
            a0 = dot2f(as_h2(f0a.x), as_h2(v0.x), a0);
            a1 = dot2f(as_h2(f1a.x), as_h2(v1.x), a1);
            a2 = dot2f(as_h2(f2a.x), as_h2(v2.x), a2);
            a3 = dot2f(as_h2(f3a.x), as_h2(v3.x), a3);
            a0 = dot2f(as_h2(f0a.y), as_h2(v0.y), a0);
            a1 = dot2f(as_h2(f1a.y), as_h2(v1.y), a1);
            a2 = dot2f(as_h2(f2a.y), as_h2(v2.y), a2);
            a3 = dot2f(as_h2(f3a.y), as_h2(v3.y), a3);
            a0 = dot2f(as_h2(f0b.x), as_h2(v0.z), a0);
            a1 = dot2f(as_h2(f1b.x), as_h2(v1.z), a1);
            a2 = dot2f(as_h2(f2b.x), as_h2(v2.z), a2);
            a3 = dot2f(as_h2(f3b.x), as_h2(v3.z), a3);
            a0 = dot2f(as_h2(f0b.y), as_h2(v0.w), a0);
            a1 = dot2f(as_h2(f1b.y), as_h2(v1.w), a1);
            a2 = dot2f(as_h2(f2b.y), as_h2(v2.w), a2);
            a3 = dot2f(as_h2(f3b.y), as_h2(v3.w), a3);
          }
          out[(size_t)(t0+tt)*NB*NC + (size_t)b*NC + j] =
              (a0+a1) + (a2+a3) + fcb[j];
        }
      }
    }
    __syncthreads();   // hist reused next chunk
  }

  // ---------- final hT / cT ----------
  if (l < 16){
    hT[(size_t)b*NH + w*16 + l] = (float)hbuf[p][w*16 + l];
    cT[(size_t)b*NH + w*16 + l] = cst;
  }
}

extern "C" void kernel_launch(void* const* d_in, const int* in_sizes, int n_in,
                              void* d_out, int out_size, void* d_ws, size_t ws_size,
                              hipStream_t stream) {
  (void)in_sizes; (void)n_in; (void)d_ws; (void)ws_size; (void)out_size;
  const float* x   = (const float*)d_in[0];
  const float* h0  = (const float*)d_in[1];
  const float* c0  = (const float*)d_in[2];
  const float* Wih = (const float*)d_in[3];
  const float* Whh = (const float*)d_in[4];
  const float* bih = (const float*)d_in[5];
  const float* bhh = (const float*)d_in[6];
  const float* fcW = (const float*)d_in[7];
  const float* fcb = (const float*)d_in[8];
  float* out = (float*)d_out;
  float* hT  = out + (size_t)TSTEPS*NB*NC;   // 4,718,592
  float* cT  = hT + (size_t)NB*NH;           // +32,768
  hipLaunchKernelGGL(lstm_mfma, dim3(NB), dim3(512), 0, stream,
                     x, h0, c0, Wih, Whh, bih, bhh, fcW, fcb, out, hT, cT);
}